// Round 1
// baseline (305.303 us; speedup 1.0000x reference)
//
#include <hip/hip_runtime.h>

// Adaptive embedding: partition tokens by cluster (wave-aggregated atomics),
// then gathered bf16-MFMA GEMM per cluster with DIRECT global->register
// fragment loads (no LDS operand staging, zero K-loop barriers, double-
// buffered prefetch):
//   out[tok,:] = 32 * emb_c[id] @ proj_c^T   (fp32 in, bf16 MFMA, fp32 out)
//
// d_in[0] ids i32[16384]; (emb_i f32[*,d_i], proj_i f32[1024,d_i]), d_i=1024/256/64/16
// out f32 [16384,1024]. ws: int cnt[4]; int lists[4][16384].

constexpr int NTOK  = 16384;
constexpr int DPROJ = 1024;
constexpr float EMB_SCALE = 32.0f;

typedef __attribute__((ext_vector_type(8))) short short8;   // 8 bf16 (4 VGPR)
typedef __attribute__((ext_vector_type(4))) float float4v;  // MFMA C/D

__global__ __launch_bounds__(256) void partition_kernel(
    const int* __restrict__ ids, int* __restrict__ cnt, int* __restrict__ lists)
{
    int t = blockIdx.x * 256 + threadIdx.x;
    int id = ids[t];
    int c = (id >= 200000) ? 3 : (id >= 40000) ? 2 : (id >= 20000) ? 1 : 0;
    int lane = threadIdx.x & 63;
    unsigned long long lt = (1ull << lane) - 1ull;
    int pos = 0;
#pragma unroll
    for (int i = 0; i < 4; ++i) {
        unsigned long long m = __ballot(c == i);
        int b = 0;
        if (lane == 0 && m) b = atomicAdd(&cnt[i], (int)__popcll(m));
        b = __shfl(b, 0);
        if (c == i) pos = b + (int)__popcll(m & lt);
    }
    lists[c * NTOK + pos] = t;
}

__device__ __forceinline__ short f2bf(float f) {  // RNE; inputs finite
    unsigned u = __builtin_bit_cast(unsigned, f);
    u += 0x7FFFu + ((u >> 16) & 1u);
    return (short)(u >> 16);
}

__device__ __forceinline__ short8 cvt8(float4 a, float4 b) {
    short8 r = { f2bf(a.x), f2bf(a.y), f2bf(a.z), f2bf(a.w),
                 f2bf(b.x), f2bf(b.y), f2bf(b.z), f2bf(b.w) };
    return r;
}

// 64(tokens) x 128(cols) tile, 4 waves; wave w owns cols [w*32, w*32+32).
// MFMA fragments loaded straight from global memory:
//   A-frag lane(col,quad): emb[row(m*16+col)][k0 + quad*8 .. +8]  (2x float4)
//   B-frag lane(col,quad): proj[n0+wv*32+n*16+col][k0 + quad*8 .. +8]
// Double-buffered: chunk k+1 loads issue before chunk k's convert+MFMA.
template<int D>
__device__ __forceinline__ void gemm_tile(
    const int* __restrict__ ids,
    const float* __restrict__ emb,
    const float* __restrict__ proj,
    const int* __restrict__ list,
    int count, int lo,
    float* __restrict__ out,
    int* smTok, int* smRow)
{
    const int m0 = blockIdx.x * 64;          // grid transposed: x = m-tile
    if (m0 >= count) return;
    const int n0 = blockIdx.y * 128;         // y = n-tile (8) -> same XCD per m-tile
    const int tid  = threadIdx.x;
    const int lane = tid & 63;
    const int wv   = tid >> 6;
    const int col  = lane & 15;
    const int quad = lane >> 4;
    const int kq   = quad * 8;               // lane's k-offset within a 32-chunk

    if (tid < 64) {
        int m = m0 + tid;
        int tok = (m < count) ? list[m] : -1;
        smTok[tid] = tok;
        smRow[tid] = (tok >= 0) ? (ids[tok] - lo) : 0;
    }
    __syncthreads();                          // only barrier in the kernel

    const float* aptr[4];
#pragma unroll
    for (int m = 0; m < 4; ++m)
        aptr[m] = emb + (size_t)smRow[m * 16 + col] * D + kq;
    const float* bptr[2];
#pragma unroll
    for (int n = 0; n < 2; ++n)
        bptr[n] = proj + (size_t)(n0 + wv * 32 + n * 16 + col) * D + kq;

    // D==16: only quads 0,1 carry valid k (K=32 MFMA, zero-pad upper half)
    const bool kvalid = (D >= 32) || (kq < D);

    float4v acc[4][2] = {};
    float4 A0[4][2], B0[2][2], A1[4][2], B1[2][2];

    auto loadc = [&](int kc, float4 (&A)[4][2], float4 (&B)[2][2]) {
        const int off = kc * 32;
#pragma unroll
        for (int m = 0; m < 4; ++m) {
            if (kvalid) {
                A[m][0] = *(const float4*)(aptr[m] + off);
                A[m][1] = *(const float4*)(aptr[m] + off + 4);
            } else {
                A[m][0] = float4{}; A[m][1] = float4{};
            }
        }
#pragma unroll
        for (int n = 0; n < 2; ++n) {
            if (kvalid) {
                B[n][0] = *(const float4*)(bptr[n] + off);
                B[n][1] = *(const float4*)(bptr[n] + off + 4);
            } else {
                B[n][0] = float4{}; B[n][1] = float4{};
            }
        }
    };

    auto computec = [&](float4 (&A)[4][2], float4 (&B)[2][2]) {
        short8 af[4], bf[2];
#pragma unroll
        for (int m = 0; m < 4; ++m) af[m] = cvt8(A[m][0], A[m][1]);
#pragma unroll
        for (int n = 0; n < 2; ++n) bf[n] = cvt8(B[n][0], B[n][1]);
#pragma unroll
        for (int m = 0; m < 4; ++m)
#pragma unroll
            for (int n = 0; n < 2; ++n)
                acc[m][n] = __builtin_amdgcn_mfma_f32_16x16x32_bf16(
                    af[m], bf[n], acc[m][n], 0, 0, 0);
    };

    constexpr int CHUNKS = (D + 31) / 32;     // 32 / 8 / 2 / 1
    loadc(0, A0, B0);
#pragma unroll 1
    for (int kc = 0; kc < CHUNKS; kc += 2) {
        if (kc + 1 < CHUNKS) loadc(kc + 1, A1, B1);
        computec(A0, B0);
        if (kc + 1 < CHUNKS) {
            if (kc + 2 < CHUNKS) loadc(kc + 2, A0, B0);
            computec(A1, B1);
        }
    }

    // C/D layout: col = lane&15, row = quad*4 + reg
#pragma unroll
    for (int m = 0; m < 4; ++m) {
#pragma unroll
        for (int r = 0; r < 4; ++r) {
            int tok = smTok[m * 16 + quad * 4 + r];
            if (tok < 0) continue;
            float* op = out + (size_t)tok * DPROJ + n0 + wv * 32 + col;
            op[0]  = acc[m][0][r] * EMB_SCALE;
            op[16] = acc[m][1][r] * EMB_SCALE;
        }
    }
}

__global__ __launch_bounds__(256, 3) void adaptive_emb_gemm(
    const int* __restrict__ ids,
    const float* __restrict__ e0, const float* __restrict__ p0,
    const float* __restrict__ e1, const float* __restrict__ p1,
    const float* __restrict__ e2, const float* __restrict__ p2,
    const float* __restrict__ e3, const float* __restrict__ p3,
    const int* __restrict__ cnt, const int* __restrict__ lists,
    float* __restrict__ out)
{
    __shared__ int smTok[64];
    __shared__ int smRow[64];

    switch (blockIdx.z) {
    case 0: gemm_tile<1024>(ids, e0, p0, lists,          cnt[0], 0,      out, smTok, smRow); break;
    case 1: gemm_tile<256> (ids, e1, p1, lists + NTOK,   cnt[1], 20000,  out, smTok, smRow); break;
    case 2: gemm_tile<64>  (ids, e2, p2, lists + 2*NTOK, cnt[2], 40000,  out, smTok, smRow); break;
    case 3: gemm_tile<16>  (ids, e3, p3, lists + 3*NTOK, cnt[3], 200000, out, smTok, smRow); break;
    }
}

extern "C" void kernel_launch(void* const* d_in, const int* in_sizes, int n_in,
                              void* d_out, int out_size, void* d_ws, size_t ws_size,
                              hipStream_t stream) {
    const int*   ids = (const int*)d_in[0];
    const float* e0  = (const float*)d_in[1];
    const float* p0  = (const float*)d_in[2];
    const float* e1  = (const float*)d_in[3];
    const float* p1  = (const float*)d_in[4];
    const float* e2  = (const float*)d_in[5];
    const float* p2  = (const float*)d_in[6];
    const float* e3  = (const float*)d_in[7];
    const float* p3  = (const float*)d_in[8];
    float* out = (float*)d_out;

    int* cnt   = (int*)d_ws;
    int* lists = cnt + 4;

    hipMemsetAsync(cnt, 0, 4 * sizeof(int), stream);
    partition_kernel<<<dim3(NTOK / 256), 256, 0, stream>>>(ids, cnt, lists);

    // x = m-tile (worst case 256), y = n-tile (8), z = cluster.
    // Transposed vs before: the 8 n-tiles sharing one A-gather differ by 256
    // in linear block id (256 % 8 == 0) -> same XCD -> L2-local emb rows.
    dim3 grid(NTOK / 64, DPROJ / 128, 4);
    adaptive_emb_gemm<<<grid, 256, 0, stream>>>(
        ids, e0, p0, e1, p1, e2, p2, e3, p3, cnt, lists, out);
}

// Round 2
// 233.880 us; speedup vs baseline: 1.3054x; 1.3054x over previous
//
#include <hip/hip_runtime.h>

// Adaptive embedding: partition tokens by cluster (wave-aggregated atomics),
// then gathered bf16-MFMA GEMM per cluster.
//   out[tok,:] = 32 * emb_c[id] @ proj_c^T   (fp32 in, bf16 MFMA, fp32 out)
//
// Pipeline (per 32-wide K-chunk): double-buffered LDS, depth-2 register
// prefetch, ONE raw s_barrier per chunk with lgkmcnt-only drain so the
// prefetch global loads stay in flight across barriers (no vmcnt(0) drain —
// __syncthreads would kill the pipeline).
//
// d_in[0] ids i32[16384]; (emb_i f32[*,d_i], proj_i f32[1024,d_i]), d_i=1024/256/64/16
// out f32 [16384,1024]. ws: int cnt[4]; int lists[4][16384].

constexpr int NTOK  = 16384;
constexpr int DPROJ = 1024;
constexpr float EMB_SCALE = 32.0f;

typedef __attribute__((ext_vector_type(8))) short short8;   // 8 bf16 (4 VGPR)
typedef __attribute__((ext_vector_type(4))) float float4v;  // MFMA C/D

__global__ __launch_bounds__(256) void partition_kernel(
    const int* __restrict__ ids, int* __restrict__ cnt, int* __restrict__ lists)
{
    int t = blockIdx.x * 256 + threadIdx.x;
    int id = ids[t];
    int c = (id >= 200000) ? 3 : (id >= 40000) ? 2 : (id >= 20000) ? 1 : 0;
    int lane = threadIdx.x & 63;
    unsigned long long lt = (1ull << lane) - 1ull;
    int pos = 0;
#pragma unroll
    for (int i = 0; i < 4; ++i) {
        unsigned long long m = __ballot(c == i);
        int b = 0;
        if (lane == 0 && m) b = atomicAdd(&cnt[i], (int)__popcll(m));
        b = __shfl(b, 0);
        if (c == i) pos = b + (int)__popcll(m & lt);
    }
    lists[c * NTOK + pos] = t;
}

__device__ __forceinline__ short f2bf(float f) {  // RNE; inputs finite
    unsigned u = __builtin_bit_cast(unsigned, f);
    u += 0x7FFFu + ((u >> 16) & 1u);
    return (short)(u >> 16);
}

__device__ __forceinline__ short8 cvt8(float4 a, float4 b) {
    short8 r = { f2bf(a.x), f2bf(a.y), f2bf(a.z), f2bf(a.w),
                 f2bf(b.x), f2bf(b.y), f2bf(b.z), f2bf(b.w) };
    return r;
}

struct StageRegs { float4 a0, a1, b0, b1, b2, b3; };  // named members: no dyn idx

// 64(tokens) x 128(cols) tile, 4 waves; wave w owns cols [w*32, w*32+32).
// LDS bf16 tiles padded to 40 shorts/row (<=2-way bank aliasing on b128 reads).
template<int D>
__device__ __forceinline__ void gemm_tile(
    const int* __restrict__ ids,
    const float* __restrict__ emb,
    const float* __restrict__ proj,
    const int* __restrict__ list,
    int count, int lo,
    float* __restrict__ out,
    short (&Asm)[2][64][40], short (&Bsm)[2][128][40],
    int* smTok, int* smRow)
{
    const int m0 = blockIdx.x * 64;          // x = m-tile
    if (m0 >= count) return;
    const int n0 = blockIdx.y * 128;         // y = n-tile: ids differ by 256 ≡ 0 mod 8
    const int tid  = threadIdx.x;            //              -> same XCD, A L2-shared
    const int lane = tid & 63;
    const int wv   = tid >> 6;
    const int col  = lane & 15;
    const int quad = lane >> 4;

    if (tid < 64) {
        int m = m0 + tid;
        int tok = (m < count) ? list[m] : -1;
        smTok[tid] = tok;
        smRow[tid] = (tok >= 0) ? (ids[tok] - lo) : 0;
    }
    __syncthreads();                          // smRow visible (vmcnt drain ok here)

    const int ar = tid >> 2, ac = (tid & 3) * 8;    // A: 8 floats/thread
    const int br = tid >> 1, bc = (tid & 1) * 16;   // B: 16 floats/thread
    const float* arow = emb  + (size_t)smRow[ar] * D + ac;
    const float* brow = proj + (size_t)(n0 + br) * D + bc;

    auto stage = [&](int kc, StageRegs& R) {        // issue global loads only
        const int k0 = kc * 32;
        if (D >= 32 || ac + 8 <= D) {
            R.a0 = *(const float4*)(arow + k0);
            R.a1 = *(const float4*)(arow + k0 + 4);
        } else { R.a0 = float4{}; R.a1 = float4{}; }
        if (D >= 32 || bc + 16 <= D) {
            R.b0 = *(const float4*)(brow + k0);
            R.b1 = *(const float4*)(brow + k0 + 4);
            R.b2 = *(const float4*)(brow + k0 + 8);
            R.b3 = *(const float4*)(brow + k0 + 12);
        } else { R.b0 = float4{}; R.b1 = float4{}; R.b2 = float4{}; R.b3 = float4{}; }
    };

    auto commit = [&](const StageRegs& R, int buf) { // cvt + LDS write (vmcnt dep)
        *(short8*)&Asm[buf][ar][ac]     = cvt8(R.a0, R.a1);
        *(short8*)&Bsm[buf][br][bc]     = cvt8(R.b0, R.b1);
        *(short8*)&Bsm[buf][br][bc + 8] = cvt8(R.b2, R.b3);
    };

    float4v acc[4][2] = {};
    constexpr int CHUNKS = (D + 31) / 32;     // 32 / 8 / 2 / 1

    StageRegs R0, R1;
    stage(0, R0);
    if (CHUNKS > 1) stage(1, R1);
    commit(R0, 0);
    asm volatile("s_waitcnt lgkmcnt(0)" ::: "memory");
    __builtin_amdgcn_s_barrier();

    // body(kc): frags<-buf[kc&1]; prefetch kc+2 into freed regs; MFMA;
    //           commit kc+1 -> buf^1; lgkm-only barrier (gloads stay in flight)
    auto body = [&](int kc, int buf, StageRegs& Rfree, StageRegs& Rnext) {
        if (kc + 2 < CHUNKS) stage(kc + 2, Rfree);
        short8 af[4], bf[2];
#pragma unroll
        for (int m = 0; m < 4; ++m)
            af[m] = *(const short8*)&Asm[buf][m * 16 + col][quad * 8];
#pragma unroll
        for (int n = 0; n < 2; ++n)
            bf[n] = *(const short8*)&Bsm[buf][wv * 32 + n * 16 + col][quad * 8];
#pragma unroll
        for (int m = 0; m < 4; ++m)
#pragma unroll
            for (int n = 0; n < 2; ++n)
                acc[m][n] = __builtin_amdgcn_mfma_f32_16x16x32_bf16(
                    af[m], bf[n], acc[m][n], 0, 0, 0);
        if (kc + 1 < CHUNKS) commit(Rnext, buf ^ 1);
        asm volatile("s_waitcnt lgkmcnt(0)" ::: "memory");
        __builtin_amdgcn_s_barrier();
    };

#pragma unroll 1
    for (int kc = 0; kc < CHUNKS; kc += 2) {
        body(kc, 0, R0, R1);
        if (kc + 1 < CHUNKS) body(kc + 1, 1, R1, R0);
    }

    // C/D layout: col = lane&15, row = quad*4 + reg
#pragma unroll
    for (int m = 0; m < 4; ++m) {
#pragma unroll
        for (int r = 0; r < 4; ++r) {
            int tok = smTok[m * 16 + quad * 4 + r];
            if (tok < 0) continue;
            float* op = out + (size_t)tok * DPROJ + n0 + wv * 32 + col;
            op[0]  = acc[m][0][r] * EMB_SCALE;
            op[16] = acc[m][1][r] * EMB_SCALE;
        }
    }
}

__global__ __launch_bounds__(256) void adaptive_emb_gemm(
    const int* __restrict__ ids,
    const float* __restrict__ e0, const float* __restrict__ p0,
    const float* __restrict__ e1, const float* __restrict__ p1,
    const float* __restrict__ e2, const float* __restrict__ p2,
    const float* __restrict__ e3, const float* __restrict__ p3,
    const int* __restrict__ cnt, const int* __restrict__ lists,
    float* __restrict__ out)
{
    __shared__ short Asm[2][64][40];
    __shared__ short Bsm[2][128][40];
    __shared__ int smTok[64];
    __shared__ int smRow[64];

    switch (blockIdx.z) {
    case 0: gemm_tile<1024>(ids, e0, p0, lists,          cnt[0], 0,      out, Asm, Bsm, smTok, smRow); break;
    case 1: gemm_tile<256> (ids, e1, p1, lists + NTOK,   cnt[1], 20000,  out, Asm, Bsm, smTok, smRow); break;
    case 2: gemm_tile<64>  (ids, e2, p2, lists + 2*NTOK, cnt[2], 40000,  out, Asm, Bsm, smTok, smRow); break;
    case 3: gemm_tile<16>  (ids, e3, p3, lists + 3*NTOK, cnt[3], 200000, out, Asm, Bsm, smTok, smRow); break;
    }
}

extern "C" void kernel_launch(void* const* d_in, const int* in_sizes, int n_in,
                              void* d_out, int out_size, void* d_ws, size_t ws_size,
                              hipStream_t stream) {
    const int*   ids = (const int*)d_in[0];
    const float* e0  = (const float*)d_in[1];
    const float* p0  = (const float*)d_in[2];
    const float* e1  = (const float*)d_in[3];
    const float* p1  = (const float*)d_in[4];
    const float* e2  = (const float*)d_in[5];
    const float* p2  = (const float*)d_in[6];
    const float* e3  = (const float*)d_in[7];
    const float* p3  = (const float*)d_in[8];
    float* out = (float*)d_out;

    int* cnt   = (int*)d_ws;
    int* lists = cnt + 4;

    hipMemsetAsync(cnt, 0, 4 * sizeof(int), stream);
    partition_kernel<<<dim3(NTOK / 256), 256, 0, stream>>>(ids, cnt, lists);

    // x = m-tile (worst case 256), y = n-tile (8), z = cluster.
    // The 8 n-tiles sharing one A-gather differ by 256 in linear block id
    // (256 % 8 == 0) -> same XCD -> gathered emb rows fetched once per tile row.
    dim3 grid(NTOK / 64, DPROJ / 128, 4);
    adaptive_emb_gemm<<<grid, 256, 0, stream>>>(
        ids, e0, p0, e1, p1, e2, p2, e3, p3, cnt, lists, out);
}